// Round 2
// baseline (867.083 us; speedup 1.0000x reference)
//
#include <hip/hip_runtime.h>

// LSTM, T=2048 steps, B=2048, IN=5, H=10, fp32. Output [T*B, H].
// Latency/issue-bound on the per-step serial recurrence -> minimize both the
// dependence chain and the per-step instruction count.
//
// Structure (round 0): ONE batch per wave (lanes 0..9 = hidden units). The h
// vector is wave-uniform, so the per-step cross-lane broadcast is
// v_readlane_b32 (VALU-class, register-scoreboard deps) -- no LDS pipe, no
// s_waitcnt lgkmcnt(0) on the recurrence chain (the old ds_bpermute version
// also dragged the x flat-loads into that wait -> ~900 cy/step).
//
// This round:
//  - Weights/biases pre-scaled by -log2(e) (i,f,o) and -2*log2(e) (g), so the
//    gate accumulators land directly in exp2's argument domain: kills the 4
//    per-gate v_mul on the chain.
//  - Cell state kept in scaled domain cs2 = -2*log2(e)*c: tanh(c') becomes
//    exp2(cs2') directly -- kills the 5th chain v_mul. Same op count in the
//    g-gate (constants folded into the existing fmaf).
//  - Last PF-step window peeled into a refill-free epilogue: removes the
//    per-step tail clamp (s_min + addr ops) from the hot loop.
//
// 2048 blocks x 64 threads = 2 waves/SIMD; x-prefetch ring PF=8 keeps
// outstanding vmcnt ops (40 loads + stores) under the 6-bit limit of 63.

#define T_STEPS 2048
#define BATCH   2048
#define NIN     5
#define NH      10
#define PF      8

typedef float v2f __attribute__((ext_vector_type(2)));

__device__ __forceinline__ float hw_exp2(float v) { return __builtin_amdgcn_exp2f(v); }
__device__ __forceinline__ float hw_rcp(float v)  { return __builtin_amdgcn_rcpf(v); }
__device__ __forceinline__ float readlane_f(float v, int srclane) {
    return __builtin_bit_cast(float,
        __builtin_amdgcn_readlane(__builtin_bit_cast(int, v), srclane));
}
__device__ __forceinline__ v2f splat2(float v) { v2f r; r.x = v; r.y = v; return r; }

__global__ __launch_bounds__(64) void lstm_fused_kernel(
    const float* __restrict__ x,   const float* __restrict__ hx0,
    const float* __restrict__ cx0, const float* __restrict__ Wih,
    const float* __restrict__ Whh, const float* __restrict__ bih,
    const float* __restrict__ bhh, float* __restrict__ out)
{
    const float L2E  = 1.4426950408889634f;   //  log2(e)
    const float L2E2 = 2.8853900817779268f;   //  2*log2(e)
    const float NL2E  = -1.4426950408889634f; // -log2(e)   (i,f,o scale)
    const float NL2E2 = -2.8853900817779268f; // -2*log2(e) (g scale, c domain)

    const int lane = threadIdx.x;
    int j = lane;                   // hidden unit 0..9; spare lanes clamp to 9
    if (j > NH - 1) j = NH - 1;
    const bool jval = (lane < NH);

    const int b = blockIdx.x;       // ONE batch per wave

    // torch LSTMCell gate rows: i:[0,10) f:[10,20) g:[20,30) o:[30,40)
    const int ri = j, rf = NH + j, rg = 2 * NH + j, ro = 3 * NH + j;

    // Per-lane weights, packed (i,f) and (g,o), PRE-SCALED into exp2 domain.
    v2f wxif[NIN], wxgo[NIN], whif[NH], whgo[NH];
#pragma unroll
    for (int k = 0; k < NIN; ++k) {
        wxif[k].x = NL2E  * Wih[ri * NIN + k];  wxif[k].y = NL2E * Wih[rf * NIN + k];
        wxgo[k].x = NL2E2 * Wih[rg * NIN + k];  wxgo[k].y = NL2E * Wih[ro * NIN + k];
    }
#pragma unroll
    for (int k = 0; k < NH; ++k) {
        whif[k].x = NL2E  * Whh[ri * NH + k];   whif[k].y = NL2E * Whh[rf * NH + k];
        whgo[k].x = NL2E2 * Whh[rg * NH + k];   whgo[k].y = NL2E * Whh[ro * NH + k];
    }
    v2f bif, bgo;
    bif.x = NL2E  * (bih[ri] + bhh[ri]);  bif.y = NL2E * (bih[rf] + bhh[rf]);
    bgo.x = NL2E2 * (bih[rg] + bhh[rg]);  bgo.y = NL2E * (bih[ro] + bhh[ro]);

    // Full h vector in every lane (refreshed via v_readlane each step).
    float hv[NH];
#pragma unroll
    for (int k = 0; k < NH; ++k) hv[k] = hx0[b * NH + k];
    // Cell state in scaled domain: cs2 = -2*log2(e) * c  (lane-local).
    float cs2 = NL2E2 * cx0[b * NH + j];

    // Opaque zero: keeps the x base address formally lane-dependent so the
    // prefetch stays on the vector-memory path (vmcnt, in-order) instead of
    // being scalarized to s_load (SMEM completes out-of-order -> lgkmcnt(0)
    // drains would land on the chain).
    int vzero;
    asm volatile("v_mov_b32 %0, 0" : "=v"(vzero));
    const float* xb = x + (size_t)b * NIN + vzero;

    // PF-deep x prefetch ring (all lanes load the same 5 floats; L1 broadcast).
    float xr[PF][NIN];
#pragma unroll
    for (int q = 0; q < PF; ++q)
#pragma unroll
        for (int k = 0; k < NIN; ++k)
            xr[q][k] = xb[(size_t)q * (BATCH * NIN) + k];

    float* outp = out + (size_t)b * NH + j;

    // ---- one LSTM step (gates already in exp2 domain) ----
#define LSTM_STEP(QQ, TT, DO_REFILL)                                          \
    {                                                                         \
        /* x-dot: independent of hv -> fills the readlane shadow */           \
        v2f aif0 = bif, ago0 = bgo;                                           \
        v2f aif1 = splat2(0.0f), ago1 = splat2(0.0f);                         \
        {                                                                     \
            v2f xx0 = splat2(xr[QQ][0]);                                      \
            v2f xx1 = splat2(xr[QQ][1]);                                      \
            v2f xx2 = splat2(xr[QQ][2]);                                      \
            v2f xx3 = splat2(xr[QQ][3]);                                      \
            v2f xx4 = splat2(xr[QQ][4]);                                      \
            aif0 += xx0 * wxif[0];  ago0 += xx0 * wxgo[0];                    \
            aif1 += xx1 * wxif[1];  ago1 += xx1 * wxgo[1];                    \
            aif0 += xx2 * wxif[2];  ago0 += xx2 * wxgo[2];                    \
            aif1 += xx3 * wxif[3];  ago1 += xx3 * wxgo[3];                    \
            aif0 += xx4 * wxif[4];  ago0 += xx4 * wxgo[4];                    \
        }                                                                     \
        if (DO_REFILL) {                                                      \
            const int tn = (TT) + PF;                                         \
            _Pragma("unroll")                                                 \
            for (int k = 0; k < NIN; ++k)                                     \
                xr[QQ][k] = xb[(size_t)tn * (BATCH * NIN) + k];               \
        }                                                                     \
        /* h-dot: hv[k] arrive via readlane (register deps, no waitcnt) */    \
        _Pragma("unroll")                                                     \
        for (int k = 0; k < NH; k += 2) {                                     \
            v2f h0 = splat2(hv[k]);                                           \
            v2f h1 = splat2(hv[k + 1]);                                       \
            aif0 += h0 * whif[k];      ago0 += h0 * whgo[k];                  \
            aif1 += h1 * whif[k + 1];  ago1 += h1 * whgo[k + 1];              \
        }                                                                     \
        const v2f aif = aif0 + aif1;                                          \
        const v2f ago = ago0 + ago1;                                          \
        /* gates: accumulators are already exp2 arguments */                  \
        const float si  = hw_rcp(1.0f + hw_exp2(aif.x));                      \
        const float sf  = hw_rcp(1.0f + hw_exp2(aif.y));                      \
        const float rg_ = hw_rcp(1.0f + hw_exp2(ago.x));                      \
        const float so  = hw_rcp(1.0f + hw_exp2(ago.y));                      \
        const float tg2 = fmaf(-2.0f * L2E2, rg_, L2E2);  /* -2L2E*tanh(g) */ \
        cs2 = fmaf(sf, cs2, si * tg2);          /* scaled-domain c update */  \
        const float tc = fmaf(2.0f, hw_rcp(1.0f + hw_exp2(cs2)), -1.0f);      \
        const float h  = so * tc;                                             \
        if (jval) outp[(size_t)(TT) * (BATCH * NH)] = h;                      \
        /* sole cross-lane op: wave-wide h broadcast via VALU readlane */     \
        _Pragma("unroll")                                                     \
        for (int k = 0; k < NH; ++k)                                          \
            hv[k] = readlane_f(h, k);                                         \
    }

#pragma unroll 1
    for (int t0 = 0; t0 < T_STEPS - PF; t0 += PF) {
#pragma unroll
        for (int q = 0; q < PF; ++q) {
            LSTM_STEP(q, t0 + q, 1);
        }
    }
    // refill-free epilogue window (t = T_STEPS-PF .. T_STEPS-1)
    {
        const int t0 = T_STEPS - PF;
#pragma unroll
        for (int q = 0; q < PF; ++q) {
            LSTM_STEP(q, t0 + q, 0);
        }
    }
#undef LSTM_STEP
}

extern "C" void kernel_launch(void* const* d_in, const int* in_sizes, int n_in,
                              void* d_out, int out_size, void* d_ws, size_t ws_size,
                              hipStream_t stream) {
    const float* x   = (const float*)d_in[0];
    const float* hx0 = (const float*)d_in[1];
    const float* cx0 = (const float*)d_in[2];
    const float* Wih = (const float*)d_in[3];
    const float* Whh = (const float*)d_in[4];
    const float* bih = (const float*)d_in[5];
    const float* bhh = (const float*)d_in[6];
    float* out = (float*)d_out;

    lstm_fused_kernel<<<BATCH, 64, 0, stream>>>(x, hx0, cx0, Wih, Whh, bih, bhh, out);
}

// Round 4
// 862.080 us; speedup vs baseline: 1.0058x; 1.0058x over previous
//
#include <hip/hip_runtime.h>

// LSTM, T=2048 steps, B=2048, IN=5, H=10, fp32. Output [T*B, H].
// Round-2/3 theory: VALU-issue-bound with register demotion.
//   Round-1 counters: VALUBusy 79.9%, HBM 9.4%, VGPR_Count 76. But live state
//   is >=100 VGPRs (60 weights + 40 x-ring + accums) -> compiler demoted
//   ~40-60 regs to AGPR/scratch (launch_bounds(64) with no waves/EU hint
//   targets high occupancy = small VGPR budget), paying v_accvgpr_read/write
//   around every use: ~2.5x instruction inflation on an issue-bound kernel.
//   Grid is 2048 waves = 2/SIMD -> we can afford 256 VGPRs at ZERO occupancy
//   cost. Fix: __launch_bounds__(64, 2). Single-variable change vs round 1
//   (round 2 never ran: GPU acquisition timeout — resubmitted verbatim).
//
// Structure (unchanged): ONE batch per wave, lanes 0..9 = hidden units;
// h broadcast via v_readlane (VALU-class, no LDS/lgkmcnt on the chain);
// weights/biases pre-scaled into exp2 argument domain; cell state kept in
// scaled domain cs2 = -2*log2(e)*c; PF=8 VMEM x-prefetch ring (vzero keeps
// it on the vector path: in-order vmcnt, partial waits); refill-free peeled
// epilogue window.

#define T_STEPS 2048
#define BATCH   2048
#define NIN     5
#define NH      10
#define PF      8

typedef float v2f __attribute__((ext_vector_type(2)));

__device__ __forceinline__ float hw_exp2(float v) { return __builtin_amdgcn_exp2f(v); }
__device__ __forceinline__ float hw_rcp(float v)  { return __builtin_amdgcn_rcpf(v); }
__device__ __forceinline__ float readlane_f(float v, int srclane) {
    return __builtin_bit_cast(float,
        __builtin_amdgcn_readlane(__builtin_bit_cast(int, v), srclane));
}
__device__ __forceinline__ v2f splat2(float v) { v2f r; r.x = v; r.y = v; return r; }

__global__ __launch_bounds__(64, 2) void lstm_fused_kernel(
    const float* __restrict__ x,   const float* __restrict__ hx0,
    const float* __restrict__ cx0, const float* __restrict__ Wih,
    const float* __restrict__ Whh, const float* __restrict__ bih,
    const float* __restrict__ bhh, float* __restrict__ out)
{
    const float L2E2  = 2.8853900817779268f;  //  2*log2(e)
    const float NL2E  = -1.4426950408889634f; // -log2(e)   (i,f,o scale)
    const float NL2E2 = -2.8853900817779268f; // -2*log2(e) (g scale, c domain)

    const int lane = threadIdx.x;
    int j = lane;                   // hidden unit 0..9; spare lanes clamp to 9
    if (j > NH - 1) j = NH - 1;
    const bool jval = (lane < NH);

    const int b = blockIdx.x;       // ONE batch per wave

    // torch LSTMCell gate rows: i:[0,10) f:[10,20) g:[20,30) o:[30,40)
    const int ri = j, rf = NH + j, rg = 2 * NH + j, ro = 3 * NH + j;

    // Per-lane weights, packed (i,f) and (g,o), PRE-SCALED into exp2 domain.
    v2f wxif[NIN], wxgo[NIN], whif[NH], whgo[NH];
#pragma unroll
    for (int k = 0; k < NIN; ++k) {
        wxif[k].x = NL2E  * Wih[ri * NIN + k];  wxif[k].y = NL2E * Wih[rf * NIN + k];
        wxgo[k].x = NL2E2 * Wih[rg * NIN + k];  wxgo[k].y = NL2E * Wih[ro * NIN + k];
    }
#pragma unroll
    for (int k = 0; k < NH; ++k) {
        whif[k].x = NL2E  * Whh[ri * NH + k];   whif[k].y = NL2E * Whh[rf * NH + k];
        whgo[k].x = NL2E2 * Whh[rg * NH + k];   whgo[k].y = NL2E * Whh[ro * NH + k];
    }
    v2f bif, bgo;
    bif.x = NL2E  * (bih[ri] + bhh[ri]);  bif.y = NL2E * (bih[rf] + bhh[rf]);
    bgo.x = NL2E2 * (bih[rg] + bhh[rg]);  bgo.y = NL2E * (bih[ro] + bhh[ro]);

    // Full h vector in every lane (refreshed via v_readlane each step).
    float hv[NH];
#pragma unroll
    for (int k = 0; k < NH; ++k) hv[k] = hx0[b * NH + k];
    // Cell state in scaled domain: cs2 = -2*log2(e) * c  (lane-local).
    float cs2 = NL2E2 * cx0[b * NH + j];

    // Opaque zero: keeps the x base address formally lane-dependent so the
    // prefetch stays on the vector-memory path (vmcnt, in-order partial
    // waits) instead of being scalarized to s_load (SMEM is out-of-order ->
    // lgkmcnt(0) drains would serialize on the chain).
    int vzero;
    asm volatile("v_mov_b32 %0, 0" : "=v"(vzero));
    const float* xb = x + (size_t)b * NIN + vzero;

    // PF-deep x prefetch ring (all lanes load the same 5 floats; L1 broadcast).
    float xr[PF][NIN];
#pragma unroll
    for (int q = 0; q < PF; ++q)
#pragma unroll
        for (int k = 0; k < NIN; ++k)
            xr[q][k] = xb[(size_t)q * (BATCH * NIN) + k];

    float* outp = out + (size_t)b * NH + j;

    // ---- one LSTM step (gates already in exp2 domain) ----
#define LSTM_STEP(QQ, TT, DO_REFILL)                                          \
    {                                                                         \
        /* x-dot: independent of hv -> fills the readlane shadow */           \
        v2f aif0 = bif, ago0 = bgo;                                           \
        v2f aif1 = splat2(0.0f), ago1 = splat2(0.0f);                         \
        {                                                                     \
            v2f xx0 = splat2(xr[QQ][0]);                                      \
            v2f xx1 = splat2(xr[QQ][1]);                                      \
            v2f xx2 = splat2(xr[QQ][2]);                                      \
            v2f xx3 = splat2(xr[QQ][3]);                                      \
            v2f xx4 = splat2(xr[QQ][4]);                                      \
            aif0 += xx0 * wxif[0];  ago0 += xx0 * wxgo[0];                    \
            aif1 += xx1 * wxif[1];  ago1 += xx1 * wxgo[1];                    \
            aif0 += xx2 * wxif[2];  ago0 += xx2 * wxgo[2];                    \
            aif1 += xx3 * wxif[3];  ago1 += xx3 * wxgo[3];                    \
            aif0 += xx4 * wxif[4];  ago0 += xx4 * wxgo[4];                    \
        }                                                                     \
        if (DO_REFILL) {                                                      \
            const int tn = (TT) + PF;                                         \
            _Pragma("unroll")                                                 \
            for (int k = 0; k < NIN; ++k)                                     \
                xr[QQ][k] = xb[(size_t)tn * (BATCH * NIN) + k];               \
        }                                                                     \
        /* h-dot: hv[k] arrive via readlane (register deps, no waitcnt) */    \
        _Pragma("unroll")                                                     \
        for (int k = 0; k < NH; k += 2) {                                     \
            v2f h0 = splat2(hv[k]);                                           \
            v2f h1 = splat2(hv[k + 1]);                                       \
            aif0 += h0 * whif[k];      ago0 += h0 * whgo[k];                  \
            aif1 += h1 * whif[k + 1];  ago1 += h1 * whgo[k + 1];              \
        }                                                                     \
        const v2f aif = aif0 + aif1;                                          \
        const v2f ago = ago0 + ago1;                                          \
        /* gates: accumulators are already exp2 arguments */                  \
        const float si  = hw_rcp(1.0f + hw_exp2(aif.x));                      \
        const float sf  = hw_rcp(1.0f + hw_exp2(aif.y));                      \
        const float rg_ = hw_rcp(1.0f + hw_exp2(ago.x));                      \
        const float so  = hw_rcp(1.0f + hw_exp2(ago.y));                      \
        const float tg2 = fmaf(-2.0f * L2E2, rg_, L2E2);  /* -2L2E*tanh(g) */ \
        cs2 = fmaf(sf, cs2, si * tg2);          /* scaled-domain c update */  \
        const float tc = fmaf(2.0f, hw_rcp(1.0f + hw_exp2(cs2)), -1.0f);      \
        const float h  = so * tc;                                             \
        if (jval) outp[(size_t)(TT) * (BATCH * NH)] = h;                      \
        /* sole cross-lane op: wave-wide h broadcast via VALU readlane */     \
        _Pragma("unroll")                                                     \
        for (int k = 0; k < NH; ++k)                                          \
            hv[k] = readlane_f(h, k);                                         \
    }

#pragma unroll 1
    for (int t0 = 0; t0 < T_STEPS - PF; t0 += PF) {
#pragma unroll
        for (int q = 0; q < PF; ++q) {
            LSTM_STEP(q, t0 + q, 1);
        }
    }
    // refill-free epilogue window (t = T_STEPS-PF .. T_STEPS-1)
    {
        const int t0 = T_STEPS - PF;
#pragma unroll
        for (int q = 0; q < PF; ++q) {
            LSTM_STEP(q, t0 + q, 0);
        }
    }
#undef LSTM_STEP
}

extern "C" void kernel_launch(void* const* d_in, const int* in_sizes, int n_in,
                              void* d_out, int out_size, void* d_ws, size_t ws_size,
                              hipStream_t stream) {
    const float* x   = (const float*)d_in[0];
    const float* hx0 = (const float*)d_in[1];
    const float* cx0 = (const float*)d_in[2];
    const float* Wih = (const float*)d_in[3];
    const float* Whh = (const float*)d_in[4];
    const float* bih = (const float*)d_in[5];
    const float* bhh = (const float*)d_in[6];
    float* out = (float*)d_out;

    lstm_fused_kernel<<<BATCH, 64, 0, stream>>>(x, hx0, cx0, Wih, Whh, bih, bhh, out);
}